// Round 1
// baseline (312.020 us; speedup 1.0000x reference)
//
#include <hip/hip_runtime.h>

#define Bb 4
#define Nn 2048
#define Dd 1024
#define Rr 64
#define LN_EPS 1e-5f

typedef unsigned short u16;
typedef short bf16x8 __attribute__((ext_vector_type(8)));   // 8 bf16 in 4 VGPRs
typedef u16 u16x4v __attribute__((ext_vector_type(4)));
typedef float f32x4 __attribute__((ext_vector_type(4)));

__device__ __forceinline__ u16 f2bf(float f) {
  unsigned u = __float_as_uint(f);
  u += 0x7FFFu + ((u >> 16) & 1u);   // RNE
  return (u16)(u >> 16);
}

// ---- prep_x: x (B,N,D) f32 -> xt (B,D,N) bf16 (transposed for PV B-operand) ----
__global__ __launch_bounds__(256) void prep_x(const float* __restrict__ x,
                                              u16* __restrict__ xt) {
  __shared__ float tile[64][65];
  const int b = blockIdx.z;
  const int n0 = blockIdx.x * 64;
  const int d0 = blockIdx.y * 64;
  const int t = threadIdx.x;
  const int c = t & 63, r4 = t >> 6;
#pragma unroll
  for (int rr = 0; rr < 16; rr++) {
    int row = rr * 4 + r4;
    tile[row][c] = x[(size_t)(b * Nn + n0 + row) * Dd + d0 + c];
  }
  __syncthreads();
#pragma unroll
  for (int rr = 0; rr < 16; rr++) {
    int dd = rr * 4 + r4;
    xt[(size_t)(b * Dd + d0 + dd) * Nn + n0 + c] = f2bf(tile[c][dd]);
  }
}

// ---- prep_uv: U,V (D,R) f32 -> uvt (128,D) bf16, rows = [U^T ; V^T] ----
__global__ __launch_bounds__(256) void prep_uv(const float* __restrict__ U,
                                               const float* __restrict__ V,
                                               u16* __restrict__ uvt) {
  __shared__ float tile[64][65];
  const int which = blockIdx.x >> 4;
  const int d0 = (blockIdx.x & 15) * 64;
  const float* src = which ? V : U;
  const int t = threadIdx.x, c = t & 63, r4 = t >> 6;
#pragma unroll
  for (int rr = 0; rr < 16; rr++) {
    int row = rr * 4 + r4;
    tile[row][c] = src[(size_t)(d0 + row) * Rr + c];
  }
  __syncthreads();
#pragma unroll
  for (int rr = 0; rr < 16; rr++) {
    int r = rr * 4 + r4;
    uvt[(size_t)(which * 64 + r) * Dd + d0 + c] = f2bf(tile[c][r]);
  }
}

// ---- qscale: qs[g] = 1/sqrt(max(sum_r mask[g,r], 1)) ----
__global__ __launch_bounds__(256) void qscale_k(const float* __restrict__ mask,
                                                float* __restrict__ qs) {
  const int row = blockIdx.x * 4 + (threadIdx.x >> 6);
  const int lane = threadIdx.x & 63;
  float v = mask[(size_t)row * Rr + lane];
#pragma unroll
  for (int off = 32; off; off >>= 1) v += __shfl_xor(v, off);
  if (lane == 0) qs[row] = rsqrtf(fmaxf(v, 1.0f));
}

// ---- proj_qk: Q = (x@U)*mask, K = (x@V)*mask, bf16 out. 64 rows x 128 cols/block ----
__global__ __launch_bounds__(256) void proj_qk(const float* __restrict__ x,
    const float* __restrict__ mask, const u16* __restrict__ uvt,
    u16* __restrict__ Qo, u16* __restrict__ Ko) {
  const int t = threadIdx.x;
  const int w = t >> 6, l = t & 63, quad = l >> 4, l16 = l & 15;
  const int g0 = blockIdx.x * 64;
  f32x4 acc[4][2];
#pragma unroll
  for (int i = 0; i < 4; i++)
#pragma unroll
    for (int j = 0; j < 2; j++) acc[i][j] = (f32x4){0.f, 0.f, 0.f, 0.f};
  for (int k0 = 0; k0 < Dd; k0 += 32) {
    bf16x8 a[4];
#pragma unroll
    for (int mt = 0; mt < 4; mt++) {
      const float4* px = (const float4*)&x[(size_t)(g0 + mt * 16 + l16) * Dd + k0 + quad * 8];
      float4 x0 = px[0], x1 = px[1];
      bf16x8 av;
      av[0] = (short)f2bf(x0.x); av[1] = (short)f2bf(x0.y);
      av[2] = (short)f2bf(x0.z); av[3] = (short)f2bf(x0.w);
      av[4] = (short)f2bf(x1.x); av[5] = (short)f2bf(x1.y);
      av[6] = (short)f2bf(x1.z); av[7] = (short)f2bf(x1.w);
      a[mt] = av;
    }
    bf16x8 bfr[2];
#pragma unroll
    for (int i = 0; i < 2; i++) {
      int col = (w * 2 + i) * 16 + l16;
      bfr[i] = *(const bf16x8*)&uvt[(size_t)col * Dd + k0 + quad * 8];
    }
#pragma unroll
    for (int mt = 0; mt < 4; mt++)
#pragma unroll
      for (int i = 0; i < 2; i++)
        acc[mt][i] = __builtin_amdgcn_mfma_f32_16x16x32_bf16(a[mt], bfr[i], acc[mt][i], 0, 0, 0);
  }
#pragma unroll
  for (int mt = 0; mt < 4; mt++)
#pragma unroll
    for (int i = 0; i < 2; i++) {
      int col = (w * 2 + i) * 16 + l16;
      int r_ = col & 63;
#pragma unroll
      for (int r = 0; r < 4; r++) {
        int row = g0 + mt * 16 + quad * 4 + r;
        float v = acc[mt][i][r] * mask[(size_t)row * Rr + r_];
        u16 bv = f2bf(v);
        if (col < 64) Qo[(size_t)row * Rr + r_] = bv;
        else          Ko[(size_t)row * Rr + r_] = bv;
      }
    }
}

// ---- attn: flash-style. Block = 32 queries x 1 batch, 512 threads (8 waves).
// Wave w: S-tile (m=w&1, n=w>>1); PV D-chunk = [w*128, w*128+128).
__global__ __launch_bounds__(512, 2) void attn(const float* __restrict__ x,
    const u16* __restrict__ xt, const u16* __restrict__ Qm,
    const u16* __restrict__ Km, const float* __restrict__ qs,
    const float* __restrict__ gamma, const float* __restrict__ beta,
    float* __restrict__ out) {
  __shared__ float s_lds[32][65];
  __shared__ __align__(16) u16 p_lds[32][72];   // stride 144B: 2-way (free) bank pattern
  __shared__ float m_lds[32], l_lds[32], al_lds[32], qs_lds[32];
  __shared__ float red[2][32][8];
  const int t = threadIdx.x;
  const int w = t >> 6, l = t & 63, quad = l >> 4, l16 = l & 15;
  const int b = blockIdx.y;
  const int q0 = blockIdx.x * 32;
  const size_t xbase = (size_t)b * Nn * Dd;
  const int mw = w & 1, nw = w >> 1;
  bf16x8 qf[2];
#pragma unroll
  for (int ks = 0; ks < 2; ks++)
    qf[ks] = *(const bf16x8*)&Qm[(size_t)(b * Nn + q0 + mw * 16 + l16) * Rr + ks * 32 + quad * 8];
  if (t < 32) {
    m_lds[t] = -1e30f; l_lds[t] = 0.f;
    qs_lds[t] = qs[(size_t)b * Nn + q0 + t];
  }
  f32x4 acc[2][8];
#pragma unroll
  for (int i = 0; i < 2; i++)
#pragma unroll
    for (int j = 0; j < 8; j++) acc[i][j] = (f32x4){0.f, 0.f, 0.f, 0.f};
  __syncthreads();
#pragma unroll 1
  for (int kt = 0; kt < Nn / 64; kt++) {
    const int k0 = kt * 64;
    // ---- S = Q K^T (this wave's 16x16 tile of the 32x64 S block) ----
    f32x4 s = (f32x4){0.f, 0.f, 0.f, 0.f};
#pragma unroll
    for (int ks = 0; ks < 2; ks++) {
      bf16x8 kf = *(const bf16x8*)&Km[(size_t)(b * Nn + k0 + nw * 16 + l16) * Rr + ks * 32 + quad * 8];
      s = __builtin_amdgcn_mfma_f32_16x16x32_bf16(qf[ks], kf, s, 0, 0, 0);
    }
#pragma unroll
    for (int r = 0; r < 4; r++)
      s_lds[mw * 16 + quad * 4 + r][nw * 16 + l16] = s[r];
    __syncthreads();
    // ---- online softmax (row = t>>4, 16 threads/row, 4 cols each) ----
    {
      const int row = t >> 4, sub = t & 15;
      const float sc = qs_lds[row];
      float v0 = s_lds[row][sub * 4 + 0] * sc;
      float v1 = s_lds[row][sub * 4 + 1] * sc;
      float v2 = s_lds[row][sub * 4 + 2] * sc;
      float v3 = s_lds[row][sub * 4 + 3] * sc;
      float mx = fmaxf(fmaxf(v0, v1), fmaxf(v2, v3));
#pragma unroll
      for (int off = 1; off < 16; off <<= 1) mx = fmaxf(mx, __shfl_xor(mx, off));
      const float m_old = m_lds[row];          // read-before-write: same wave, lockstep
      const float m_new = fmaxf(m_old, mx);
      float p0 = __expf(v0 - m_new), p1 = __expf(v1 - m_new);
      float p2 = __expf(v2 - m_new), p3 = __expf(v3 - m_new);
      float rs = p0 + p1 + p2 + p3;
#pragma unroll
      for (int off = 1; off < 16; off <<= 1) rs += __shfl_xor(rs, off);
      const float alpha = __expf(m_old - m_new);
      if (sub == 0) {
        m_lds[row] = m_new;
        l_lds[row] = l_lds[row] * alpha + rs;
        al_lds[row] = alpha;
      }
      u16x4v pk;
      pk[0] = f2bf(p0); pk[1] = f2bf(p1); pk[2] = f2bf(p2); pk[3] = f2bf(p3);
      *(u16x4v*)&p_lds[row][sub * 4] = pk;
    }
    __syncthreads();
    // ---- rescale O, then O += P @ X (B-frags straight from transposed Xt) ----
    float alr[2][4];
#pragma unroll
    for (int mt = 0; mt < 2; mt++)
#pragma unroll
      for (int r = 0; r < 4; r++) alr[mt][r] = al_lds[mt * 16 + quad * 4 + r];
#pragma unroll
    for (int mt = 0; mt < 2; mt++)
#pragma unroll
      for (int nt = 0; nt < 8; nt++)
#pragma unroll
        for (int r = 0; r < 4; r++) acc[mt][nt][r] *= alr[mt][r];
#pragma unroll
    for (int ks = 0; ks < 2; ks++) {
      bf16x8 af[2];
#pragma unroll
      for (int mt = 0; mt < 2; mt++)
        af[mt] = *(const bf16x8*)&p_lds[mt * 16 + l16][ks * 32 + quad * 8];
#pragma unroll
      for (int nt = 0; nt < 8; nt++) {
        bf16x8 bf_ = *(const bf16x8*)&xt[(size_t)(b * Dd + w * 128 + nt * 16 + l16) * Nn + k0 + ks * 32 + quad * 8];
#pragma unroll
        for (int mt = 0; mt < 2; mt++)
          acc[mt][nt] = __builtin_amdgcn_mfma_f32_16x16x32_bf16(af[mt], bf_, acc[mt][nt], 0, 0, 0);
      }
    }
  }
  // ---- epilogue: delta = acc/l ; y = x + delta ; out = LN(y)*gamma + beta ----
  float linv[2][4];
#pragma unroll
  for (int mt = 0; mt < 2; mt++)
#pragma unroll
    for (int r = 0; r < 4; r++) linv[mt][r] = 1.f / l_lds[mt * 16 + quad * 4 + r];
  float psum[2][4], psq[2][4];
#pragma unroll
  for (int mt = 0; mt < 2; mt++)
#pragma unroll
    for (int r = 0; r < 4; r++) { psum[mt][r] = 0.f; psq[mt][r] = 0.f; }
#pragma unroll
  for (int mt = 0; mt < 2; mt++)
#pragma unroll
    for (int nt = 0; nt < 8; nt++) {
      const int col = w * 128 + nt * 16 + l16;
#pragma unroll
      for (int r = 0; r < 4; r++) {
        const int row = q0 + mt * 16 + quad * 4 + r;
        float y = x[xbase + (size_t)row * Dd + col] + acc[mt][nt][r] * linv[mt][r];
        acc[mt][nt][r] = y;
        psum[mt][r] += y;
        psq[mt][r] += y * y;
      }
    }
#pragma unroll
  for (int mt = 0; mt < 2; mt++)
#pragma unroll
    for (int r = 0; r < 4; r++)
#pragma unroll
      for (int off = 1; off < 16; off <<= 1) {
        psum[mt][r] += __shfl_xor(psum[mt][r], off);
        psq[mt][r] += __shfl_xor(psq[mt][r], off);
      }
  if (l16 == 0) {
#pragma unroll
    for (int mt = 0; mt < 2; mt++)
#pragma unroll
      for (int r = 0; r < 4; r++) {
        red[0][mt * 16 + quad * 4 + r][w] = psum[mt][r];
        red[1][mt * 16 + quad * 4 + r][w] = psq[mt][r];
      }
  }
  __syncthreads();
  if (t < 32) {
    float s0 = 0.f, s1 = 0.f;
#pragma unroll
    for (int i = 0; i < 8; i++) { s0 += red[0][t][i]; s1 += red[1][t][i]; }
    float mu = s0 * (1.f / Dd);
    float var = s1 * (1.f / Dd) - mu * mu;
    m_lds[t] = mu;                  // reuse as mu
    l_lds[t] = rsqrtf(var + LN_EPS); // reuse as rstd
  }
  __syncthreads();
#pragma unroll
  for (int mt = 0; mt < 2; mt++) {
    float mu[4], rstd[4];
#pragma unroll
    for (int r = 0; r < 4; r++) {
      mu[r] = m_lds[mt * 16 + quad * 4 + r];
      rstd[r] = l_lds[mt * 16 + quad * 4 + r];
    }
#pragma unroll
    for (int nt = 0; nt < 8; nt++) {
      const int col = w * 128 + nt * 16 + l16;
      const float g = gamma[col], be = beta[col];
#pragma unroll
      for (int r = 0; r < 4; r++) {
        const int row = q0 + mt * 16 + quad * 4 + r;
        out[xbase + (size_t)row * Dd + col] = (acc[mt][nt][r] - mu[r]) * rstd[r] * g + be;
      }
    }
  }
}

extern "C" void kernel_launch(void* const* d_in, const int* in_sizes, int n_in,
                              void* d_out, int out_size, void* d_ws, size_t ws_size,
                              hipStream_t stream) {
  const float* x     = (const float*)d_in[0];
  const float* mask  = (const float*)d_in[1];
  const float* U     = (const float*)d_in[2];
  const float* V     = (const float*)d_in[3];
  const float* gamma = (const float*)d_in[4];
  const float* beta  = (const float*)d_in[5];
  float* out = (float*)d_out;
  char* ws = (char*)d_ws;
  // workspace layout (~18.3 MB total)
  u16*   xt  = (u16*)ws;                                  // 16 MB  (B,D,N) bf16
  u16*   Qw  = (u16*)(ws + (size_t)(16 << 20));           // 1 MB
  u16*   Kw  = (u16*)(ws + (size_t)(17 << 20));           // 1 MB
  u16*   uvt = (u16*)(ws + (size_t)(18 << 20));           // 256 KB
  float* qsb = (float*)(ws + (size_t)(18 << 20) + (256 << 10)); // 32 KB

  prep_x <<<dim3(Nn / 64, Dd / 64, Bb), 256, 0, stream>>>(x, xt);
  prep_uv<<<32, 256, 0, stream>>>(U, V, uvt);
  qscale_k<<<(Bb * Nn) / 4, 256, 0, stream>>>(mask, qsb);
  proj_qk<<<(Bb * Nn) / 64, 256, 0, stream>>>(x, mask, uvt, Qw, Kw);
  attn   <<<dim3(Nn / 32, Bb), 512, 0, stream>>>(x, xt, Qw, Kw, qsb, gamma, beta, out);
}

// Round 2
// 278.283 us; speedup vs baseline: 1.1212x; 1.1212x over previous
//
#include <hip/hip_runtime.h>

#define Bb 4
#define Nn 2048
#define Dd 1024
#define Rr 64
#define LN_EPS 1e-5f

typedef unsigned short u16;
typedef short bf16x8 __attribute__((ext_vector_type(8)));   // 8 bf16 in 4 VGPRs
typedef u16 u16x4v __attribute__((ext_vector_type(4)));
typedef float f32x4 __attribute__((ext_vector_type(4)));

__device__ __forceinline__ u16 f2bf(float f) {
  unsigned u = __float_as_uint(f);
  u += 0x7FFFu + ((u >> 16) & 1u);   // RNE
  return (u16)(u >> 16);
}

// ---- prep_x: x (B,N,D) f32 -> xt (B,D,N) bf16 (transposed for PV B-operand) ----
__global__ __launch_bounds__(256) void prep_x(const float* __restrict__ x,
                                              u16* __restrict__ xt) {
  __shared__ float tile[64][65];
  const int b = blockIdx.z;
  const int n0 = blockIdx.x * 64;
  const int d0 = blockIdx.y * 64;
  const int t = threadIdx.x;
  const int c = t & 63, r4 = t >> 6;
#pragma unroll
  for (int rr = 0; rr < 16; rr++) {
    int row = rr * 4 + r4;
    tile[row][c] = x[(size_t)(b * Nn + n0 + row) * Dd + d0 + c];
  }
  __syncthreads();
#pragma unroll
  for (int rr = 0; rr < 16; rr++) {
    int dd = rr * 4 + r4;
    xt[(size_t)(b * Dd + d0 + dd) * Nn + n0 + c] = f2bf(tile[c][dd]);
  }
}

// ---- prep_uv: U,V (D,R) f32 -> uvt (128,D) bf16, rows = [U^T ; V^T] ----
__global__ __launch_bounds__(256) void prep_uv(const float* __restrict__ U,
                                               const float* __restrict__ V,
                                               u16* __restrict__ uvt) {
  __shared__ float tile[64][65];
  const int which = blockIdx.x >> 4;
  const int d0 = (blockIdx.x & 15) * 64;
  const float* src = which ? V : U;
  const int t = threadIdx.x, c = t & 63, r4 = t >> 6;
#pragma unroll
  for (int rr = 0; rr < 16; rr++) {
    int row = rr * 4 + r4;
    tile[row][c] = src[(size_t)(d0 + row) * Rr + c];
  }
  __syncthreads();
#pragma unroll
  for (int rr = 0; rr < 16; rr++) {
    int r = rr * 4 + r4;
    uvt[(size_t)(which * 64 + r) * Dd + d0 + c] = f2bf(tile[c][r]);
  }
}

// ---- qscale: qs[g] = 1/sqrt(max(sum_r mask[g,r], 1)) ----
__global__ __launch_bounds__(256) void qscale_k(const float* __restrict__ mask,
                                                float* __restrict__ qs) {
  const int row = blockIdx.x * 4 + (threadIdx.x >> 6);
  const int lane = threadIdx.x & 63;
  float v = mask[(size_t)row * Rr + lane];
#pragma unroll
  for (int off = 32; off; off >>= 1) v += __shfl_xor(v, off);
  if (lane == 0) qs[row] = rsqrtf(fmaxf(v, 1.0f));
}

// ---- proj_qk: Q = (x@U)*mask, K = (x@V)*mask, bf16 out. 64 rows x 128 cols/block ----
__global__ __launch_bounds__(256) void proj_qk(const float* __restrict__ x,
    const float* __restrict__ mask, const u16* __restrict__ uvt,
    u16* __restrict__ Qo, u16* __restrict__ Ko) {
  const int t = threadIdx.x;
  const int w = t >> 6, l = t & 63, quad = l >> 4, l16 = l & 15;
  const int g0 = blockIdx.x * 64;
  f32x4 acc[4][2];
#pragma unroll
  for (int i = 0; i < 4; i++)
#pragma unroll
    for (int j = 0; j < 2; j++) acc[i][j] = (f32x4){0.f, 0.f, 0.f, 0.f};
  for (int k0 = 0; k0 < Dd; k0 += 32) {
    bf16x8 a[4];
#pragma unroll
    for (int mt = 0; mt < 4; mt++) {
      const float4* px = (const float4*)&x[(size_t)(g0 + mt * 16 + l16) * Dd + k0 + quad * 8];
      float4 x0 = px[0], x1 = px[1];
      bf16x8 av;
      av[0] = (short)f2bf(x0.x); av[1] = (short)f2bf(x0.y);
      av[2] = (short)f2bf(x0.z); av[3] = (short)f2bf(x0.w);
      av[4] = (short)f2bf(x1.x); av[5] = (short)f2bf(x1.y);
      av[6] = (short)f2bf(x1.z); av[7] = (short)f2bf(x1.w);
      a[mt] = av;
    }
    bf16x8 bfr[2];
#pragma unroll
    for (int i = 0; i < 2; i++) {
      int col = (w * 2 + i) * 16 + l16;
      bfr[i] = *(const bf16x8*)&uvt[(size_t)col * Dd + k0 + quad * 8];
    }
#pragma unroll
    for (int mt = 0; mt < 4; mt++)
#pragma unroll
      for (int i = 0; i < 2; i++)
        acc[mt][i] = __builtin_amdgcn_mfma_f32_16x16x32_bf16(a[mt], bfr[i], acc[mt][i], 0, 0, 0);
  }
#pragma unroll
  for (int mt = 0; mt < 4; mt++)
#pragma unroll
    for (int i = 0; i < 2; i++) {
      int col = (w * 2 + i) * 16 + l16;
      int r_ = col & 63;
#pragma unroll
      for (int r = 0; r < 4; r++) {
        int row = g0 + mt * 16 + quad * 4 + r;
        float v = acc[mt][i][r] * mask[(size_t)row * Rr + r_];
        u16 bv = f2bf(v);
        if (col < 64) Qo[(size_t)row * Rr + r_] = bv;
        else          Ko[(size_t)row * Rr + r_] = bv;
      }
    }
}

// ---- attn: flash-style. Block = 32 queries x 1 batch, 512 threads (8 waves).
// Wave w: S-tile (m=w&1, n=w>>1); PV D-chunk = [w*128, w*128+128).
// R1: software-pipelined — all 16 Xt frags for iteration kt issued at the TOP
// of the iteration (latency covered by QK+softmax+2 barriers); K-frag
// double-buffered one iteration ahead. VGPR budget deliberately spent on
// in-flight loads (R0 had VGPR=80 -> serialized load->MFMA pairs, 8% MfmaUtil).
__global__ __launch_bounds__(512, 2) void attn(const float* __restrict__ x,
    const u16* __restrict__ xt, const u16* __restrict__ Qm,
    const u16* __restrict__ Km, const float* __restrict__ qs,
    const float* __restrict__ gamma, const float* __restrict__ beta,
    float* __restrict__ out) {
  __shared__ float s_lds[32][65];
  __shared__ __align__(16) u16 p_lds[32][72];
  __shared__ float m_lds[32], l_lds[32], al_lds[32], qs_lds[32];
  __shared__ float red[2][32][8];
  const int t = threadIdx.x;
  const int w = t >> 6, l = t & 63, quad = l >> 4, l16 = l & 15;
  const int b = blockIdx.y;
  const int q0 = blockIdx.x * 32;
  const size_t xbase = (size_t)b * Nn * Dd;
  const int mw = w & 1, nw = w >> 1;
  bf16x8 qf[2];
#pragma unroll
  for (int ks = 0; ks < 2; ks++)
    qf[ks] = *(const bf16x8*)&Qm[(size_t)(b * Nn + q0 + mw * 16 + l16) * Rr + ks * 32 + quad * 8];
  // prologue: K-frags for kt=0
  bf16x8 kf[2];
#pragma unroll
  for (int ks = 0; ks < 2; ks++)
    kf[ks] = *(const bf16x8*)&Km[(size_t)(b * Nn + 0 + nw * 16 + l16) * Rr + ks * 32 + quad * 8];
  if (t < 32) {
    m_lds[t] = -1e30f; l_lds[t] = 0.f;
    qs_lds[t] = qs[(size_t)b * Nn + q0 + t];
  }
  f32x4 acc[2][8];
#pragma unroll
  for (int i = 0; i < 2; i++)
#pragma unroll
    for (int j = 0; j < 8; j++) acc[i][j] = (f32x4){0.f, 0.f, 0.f, 0.f};
  __syncthreads();
#pragma unroll 1
  for (int kt = 0; kt < Nn / 64; kt++) {
    const int k0 = kt * 64;
    // ---- issue ALL 16 Xt frag loads for THIS iteration up front ----
    bf16x8 xf[16];
#pragma unroll
    for (int ks = 0; ks < 2; ks++)
#pragma unroll
      for (int nt = 0; nt < 8; nt++)
        xf[ks * 8 + nt] = *(const bf16x8*)&xt[(size_t)(b * Dd + w * 128 + nt * 16 + l16) * Nn + k0 + ks * 32 + quad * 8];
    // ---- prefetch next iteration's K-frags (clamped addr on last iter) ----
    const int k0n = (kt < Nn / 64 - 1) ? k0 + 64 : 0;
    bf16x8 kf_n[2];
#pragma unroll
    for (int ks = 0; ks < 2; ks++)
      kf_n[ks] = *(const bf16x8*)&Km[(size_t)(b * Nn + k0n + nw * 16 + l16) * Rr + ks * 32 + quad * 8];
    // ---- S = Q K^T (kf loaded one iteration ago — no fresh-load stall) ----
    f32x4 s = (f32x4){0.f, 0.f, 0.f, 0.f};
#pragma unroll
    for (int ks = 0; ks < 2; ks++)
      s = __builtin_amdgcn_mfma_f32_16x16x32_bf16(qf[ks], kf[ks], s, 0, 0, 0);
#pragma unroll
    for (int r = 0; r < 4; r++)
      s_lds[mw * 16 + quad * 4 + r][nw * 16 + l16] = s[r];
    __syncthreads();
    // ---- online softmax (row = t>>4, 16 threads/row, 4 cols each) ----
    {
      const int row = t >> 4, sub = t & 15;
      const float sc = qs_lds[row];
      float v0 = s_lds[row][sub * 4 + 0] * sc;
      float v1 = s_lds[row][sub * 4 + 1] * sc;
      float v2 = s_lds[row][sub * 4 + 2] * sc;
      float v3 = s_lds[row][sub * 4 + 3] * sc;
      float mx = fmaxf(fmaxf(v0, v1), fmaxf(v2, v3));
#pragma unroll
      for (int off = 1; off < 16; off <<= 1) mx = fmaxf(mx, __shfl_xor(mx, off));
      const float m_old = m_lds[row];          // same-wave read-before-write
      const float m_new = fmaxf(m_old, mx);
      float p0 = __expf(v0 - m_new), p1 = __expf(v1 - m_new);
      float p2 = __expf(v2 - m_new), p3 = __expf(v3 - m_new);
      float rs = p0 + p1 + p2 + p3;
#pragma unroll
      for (int off = 1; off < 16; off <<= 1) rs += __shfl_xor(rs, off);
      const float alpha = __expf(m_old - m_new);
      if (sub == 0) {
        m_lds[row] = m_new;
        l_lds[row] = l_lds[row] * alpha + rs;
        al_lds[row] = alpha;
      }
      u16x4v pk;
      pk[0] = f2bf(p0); pk[1] = f2bf(p1); pk[2] = f2bf(p2); pk[3] = f2bf(p3);
      *(u16x4v*)&p_lds[row][sub * 4] = pk;
    }
    __syncthreads();
    // ---- rescale O, then O += P @ X (xf issued ~2 barriers ago) ----
    float alr[2][4];
#pragma unroll
    for (int mt = 0; mt < 2; mt++)
#pragma unroll
      for (int r = 0; r < 4; r++) alr[mt][r] = al_lds[mt * 16 + quad * 4 + r];
#pragma unroll
    for (int mt = 0; mt < 2; mt++)
#pragma unroll
      for (int nt = 0; nt < 8; nt++)
#pragma unroll
        for (int r = 0; r < 4; r++) acc[mt][nt][r] *= alr[mt][r];
#pragma unroll
    for (int ks = 0; ks < 2; ks++) {
      bf16x8 af[2];
#pragma unroll
      for (int mt = 0; mt < 2; mt++)
        af[mt] = *(const bf16x8*)&p_lds[mt * 16 + l16][ks * 32 + quad * 8];
#pragma unroll
      for (int nt = 0; nt < 8; nt++) {
#pragma unroll
        for (int mt = 0; mt < 2; mt++)
          acc[mt][nt] = __builtin_amdgcn_mfma_f32_16x16x32_bf16(af[mt], xf[ks * 8 + nt], acc[mt][nt], 0, 0, 0);
      }
    }
    kf[0] = kf_n[0]; kf[1] = kf_n[1];
  }
  // ---- epilogue: delta = acc/l ; y = x + delta ; out = LN(y)*gamma + beta ----
  float linv[2][4];
#pragma unroll
  for (int mt = 0; mt < 2; mt++)
#pragma unroll
    for (int r = 0; r < 4; r++) linv[mt][r] = 1.f / l_lds[mt * 16 + quad * 4 + r];
  float psum[2][4], psq[2][4];
#pragma unroll
  for (int mt = 0; mt < 2; mt++)
#pragma unroll
    for (int r = 0; r < 4; r++) { psum[mt][r] = 0.f; psq[mt][r] = 0.f; }
#pragma unroll
  for (int mt = 0; mt < 2; mt++)
#pragma unroll
    for (int nt = 0; nt < 8; nt++) {
      const int col = w * 128 + nt * 16 + l16;
#pragma unroll
      for (int r = 0; r < 4; r++) {
        const int row = q0 + mt * 16 + quad * 4 + r;
        float y = x[xbase + (size_t)row * Dd + col] + acc[mt][nt][r] * linv[mt][r];
        acc[mt][nt][r] = y;
        psum[mt][r] += y;
        psq[mt][r] += y * y;
      }
    }
#pragma unroll
  for (int mt = 0; mt < 2; mt++)
#pragma unroll
    for (int r = 0; r < 4; r++)
#pragma unroll
      for (int off = 1; off < 16; off <<= 1) {
        psum[mt][r] += __shfl_xor(psum[mt][r], off);
        psq[mt][r] += __shfl_xor(psq[mt][r], off);
      }
  if (l16 == 0) {
#pragma unroll
    for (int mt = 0; mt < 2; mt++)
#pragma unroll
      for (int r = 0; r < 4; r++) {
        red[0][mt * 16 + quad * 4 + r][w] = psum[mt][r];
        red[1][mt * 16 + quad * 4 + r][w] = psq[mt][r];
      }
  }
  __syncthreads();
  if (t < 32) {
    float s0 = 0.f, s1 = 0.f;
#pragma unroll
    for (int i = 0; i < 8; i++) { s0 += red[0][t][i]; s1 += red[1][t][i]; }
    float mu = s0 * (1.f / Dd);
    float var = s1 * (1.f / Dd) - mu * mu;
    m_lds[t] = mu;                   // reuse as mu
    l_lds[t] = rsqrtf(var + LN_EPS); // reuse as rstd
  }
  __syncthreads();
#pragma unroll
  for (int mt = 0; mt < 2; mt++) {
    float mu[4], rstd[4];
#pragma unroll
    for (int r = 0; r < 4; r++) {
      mu[r] = m_lds[mt * 16 + quad * 4 + r];
      rstd[r] = l_lds[mt * 16 + quad * 4 + r];
    }
#pragma unroll
    for (int nt = 0; nt < 8; nt++) {
      const int col = w * 128 + nt * 16 + l16;
      const float g = gamma[col], be = beta[col];
#pragma unroll
      for (int r = 0; r < 4; r++) {
        const int row = q0 + mt * 16 + quad * 4 + r;
        out[xbase + (size_t)row * Dd + col] = (acc[mt][nt][r] - mu[r]) * rstd[r] * g + be;
      }
    }
  }
}

extern "C" void kernel_launch(void* const* d_in, const int* in_sizes, int n_in,
                              void* d_out, int out_size, void* d_ws, size_t ws_size,
                              hipStream_t stream) {
  const float* x     = (const float*)d_in[0];
  const float* mask  = (const float*)d_in[1];
  const float* U     = (const float*)d_in[2];
  const float* V     = (const float*)d_in[3];
  const float* gamma = (const float*)d_in[4];
  const float* beta  = (const float*)d_in[5];
  float* out = (float*)d_out;
  char* ws = (char*)d_ws;
  // workspace layout (~18.3 MB total)
  u16*   xt  = (u16*)ws;                                  // 16 MB  (B,D,N) bf16
  u16*   Qw  = (u16*)(ws + (size_t)(16 << 20));           // 1 MB
  u16*   Kw  = (u16*)(ws + (size_t)(17 << 20));           // 1 MB
  u16*   uvt = (u16*)(ws + (size_t)(18 << 20));           // 256 KB
  float* qsb = (float*)(ws + (size_t)(18 << 20) + (256 << 10)); // 32 KB

  prep_x <<<dim3(Nn / 64, Dd / 64, Bb), 256, 0, stream>>>(x, xt);
  prep_uv<<<32, 256, 0, stream>>>(U, V, uvt);
  qscale_k<<<(Bb * Nn) / 4, 256, 0, stream>>>(mask, qsb);
  proj_qk<<<(Bb * Nn) / 64, 256, 0, stream>>>(x, mask, uvt, Qw, Kw);
  attn   <<<dim3(Nn / 32, Bb), 512, 0, stream>>>(x, xt, Qw, Kw, qsb, gamma, beta, out);
}